// Round 10
// baseline (157.640 us; speedup 1.0000x reference)
//
#include <hip/hip_runtime.h>
#include <math.h>

#define BATCH 32
#define NPIX 160
#define LDIM 128
#define OUT_SZ 150        // 160 - 11 + 1
#define PLANE 25600       // 160*160

#define THREADS 256
// work items: stft = 19 prg x 2 pc-halves x 3 c x 32 b = 3648; ssim = 19 tiles x 3 x 32 = 1824
#define N_STFT 3648
#define N_SSIM 1824
#define N_WORK (N_STFT + N_SSIM)   // 5472 = 1824 groups of (2 stft + 1 ssim)

// e^{-i*2pi*k/12}; entries 0 / ±0.5 / ±0.866 / ±1 -> FMAs fold at compile time
__device__ constexpr float TWC[12] = { 1.f, 0.86602540f, 0.5f, 0.f, -0.5f, -0.86602540f,
                                      -1.f,-0.86602540f,-0.5f, 0.f,  0.5f,  0.86602540f};
__device__ constexpr float TWS[12] = { 0.f,-0.5f,-0.86602540f,-1.f,-0.86602540f,-0.5f,
                                       0.f, 0.5f, 0.86602540f, 1.f, 0.86602540f, 0.5f};

__device__ constexpr float GW[11] = {0.00102838f, 0.00759876f, 0.03600076f, 0.10936070f,
                                     0.21300554f, 0.26601172f, 0.21300554f, 0.10936070f,
                                     0.03600076f, 0.00759876f, 0.00102838f};

// minimax atan poly, max err ~1e-6 rad (validated R7/R9, absmax 0.0)
__device__ __forceinline__ float fast_atan2f(float y, float x) {
    float ax = fabsf(x), ay = fabsf(y);
    float mx = fmaxf(ax, ay), mn = fminf(ax, ay);
    float z = mn / mx;
    float z2 = z * z;
    float p = fmaf(z2, -0.01172120f, 0.05265332f);
    p = fmaf(z2, p, -0.11643287f);
    p = fmaf(z2, p, 0.19354346f);
    p = fmaf(z2, p, -0.33262347f);
    p = fmaf(z2, p, 0.99997726f);
    p = p * z;
    if (ay > ax) p = 1.57079632679489662f - p;
    if (x < 0.f) p = 3.14159265358979323f - p;
    return (y < 0.f) ? -p : p;
}

// ---------------- transpose: NHWC -> planar [img][b][c][row][col]; block 1600 = KLD ----------------
__global__ __launch_bounds__(256) void transpose_kernel(const float* __restrict__ xin,
                                                        const float* __restrict__ xout,
                                                        const float* __restrict__ mean,
                                                        const float* __restrict__ logvar,
                                                        float* __restrict__ Pl,
                                                        float* __restrict__ out) {
    if (blockIdx.x == 1600) {
        float a = 0.f;
        for (int i = threadIdx.x; i < BATCH * LDIM; i += 256) {
            float m = mean[i], lv = logvar[i];
            a += -0.5f * (1.f + lv - expf(lv) - m * m) * (1.f / 32.f);
        }
        #pragma unroll
        for (int o = 32; o > 0; o >>= 1) a += __shfl_down(a, o, 64);
        __shared__ float sm[4];
        if ((threadIdx.x & 63) == 0) sm[threadIdx.x >> 6] = a;
        __syncthreads();
        if (threadIdx.x == 0) out[0] = sm[0] + sm[1] + sm[2] + sm[3];
        return;
    }
    int t = blockIdx.x * 256 + threadIdx.x;
    int colq = t % 40;
    int row  = (t / 40) % 160;
    int b    = (t / 6400) % 32;
    int img  = t / 204800;
    const float* src = img ? xout : xin;
    const float4* q = (const float4*)(src + ((size_t)(b * 160 + row) * 160 + colq * 4) * 3);
    float4 f0 = q[0], f1 = q[1], f2 = q[2];
    float* dst = Pl + (size_t)(img * 96 + b * 3) * PLANE + row * 160 + colq * 4;
    *(float4*)(dst)             = make_float4(f0.x, f0.w, f1.z, f2.y);
    *(float4*)(dst + PLANE)     = make_float4(f0.y, f1.x, f1.w, f2.z);
    *(float4*)(dst + 2 * PLANE) = make_float4(f0.z, f1.y, f2.x, f2.w);
}

// ---------------- work kernel: one item per 256-thread block ----------------
__global__ __launch_bounds__(THREADS) void work_kernel(const float* __restrict__ Pl,
                                                       float* __restrict__ out) {
    __shared__ __align__(16) float SMEM[6480];   // stft RD: 6080 fl; ssim V: 5*1296 fl
    __shared__ float sm4[4];
    const int tid = threadIdx.x;
    const int w = blockIdx.x;
    const int grp = w / 3, k3 = w % 3;
    float acc = 0.f;

    if (k3 < 2) {
        // ---- STFT item: (b, c, prg, pch) ----
        int idx = grp * 2 + k3;               // 0..3647
        int b   = idx / 114;
        int rem = idx % 114;
        int c   = rem / 38;
        int r2  = rem % 38;
        int prg = r2 / 2, pch = r2 % 2;
        int row0 = prg * 8;
        const float* base0 = Pl + (size_t)(b * 3 + c) * PLANE;
        const float* base1 = base0 + (size_t)96 * PLANE;

        // phase A: 304 tasks (r, pcl); each does BOTH images (6 float4 loads -> MLP)
        for (int t = tid; t < 304; t += THREADS) {
            int pcl = t % 19;
            int r   = t / 19;
            const float* rp0 = base0 + (row0 + r) * 160 + (pch * 19 + pcl) * 4;
            const float* rp1 = base1 + (row0 + r) * 160 + (pch * 19 + pcl) * 4;
            float4 p0 = *(const float4*)(rp0);
            float4 p1 = *(const float4*)(rp0 + 4);
            float4 p2 = *(const float4*)(rp0 + 8);
            float4 q0 = *(const float4*)(rp1);
            float4 q1 = *(const float4*)(rp1 + 4);
            float4 q2 = *(const float4*)(rp1 + 8);
            float xa[12] = {p0.x,p0.y,p0.z,p0.w, p1.x,p1.y,p1.z,p1.w, p2.x,p2.y,p2.z,p2.w};
            float xb[12] = {q0.x,q0.y,q0.z,q0.w, q1.x,q1.y,q1.z,q1.w, q2.x,q2.y,q2.z,q2.w};
            #pragma unroll
            for (int img = 0; img < 2; ++img) {
                const float* x = img ? xb : xa;
                float ev[5] = {x[1]+x[11], x[2]+x[10], x[3]+x[9], x[4]+x[8], x[5]+x[7]};
                float ov[5] = {x[1]-x[11], x[2]-x[10], x[3]-x[9], x[4]-x[8], x[5]-x[7]};
                #pragma unroll
                for (int vv = 0; vv < 5; ++vv) {
                    int v = vv + 1;
                    float re = x[0] + ((v & 1) ? -x[6] : x[6]);
                    float im = 0.f;
                    #pragma unroll
                    for (int j = 1; j <= 5; ++j) {
                        int kk = (v * j) % 12;           // compile-time
                        re = fmaf(ev[j-1], TWC[kk], re);
                        im = fmaf(ov[j-1], TWS[kk], im);
                    }
                    int i2 = (((r * 5 + vv) * 2 + img) * 19 + pcl) * 2;
                    *(float2*)&SMEM[i2] = make_float2(re, im);
                }
            }
        }
        __syncthreads();

        // phase B: 380 tasks (g, vv, pcl, u-parity); odd u uses sm, even u uses sp
        for (int t = tid; t < 380; t += THREADS) {
            int pcl  = t % 19;
            int vv   = (t / 19) % 5;
            int g    = (t / 95) & 1;
            int upar = t / 190;            // 0: u=1,3,5 ; 1: u=2,4
            float FR[3] = {0,0,0}, FI[3] = {0,0,0};
            float GR[3] = {0,0,0}, GI[3] = {0,0,0};
            #pragma unroll
            for (int i = 0; i < 6; ++i) {
                int rlo = 4 * g + i, rhi = rlo + 6;
                float2 a0 = *(const float2*)&SMEM[(((rlo * 5 + vv) * 2 + 0) * 19 + pcl) * 2];
                float2 a6 = *(const float2*)&SMEM[(((rhi * 5 + vv) * 2 + 0) * 19 + pcl) * 2];
                float2 b0 = *(const float2*)&SMEM[(((rlo * 5 + vv) * 2 + 1) * 19 + pcl) * 2];
                float2 b6 = *(const float2*)&SMEM[(((rhi * 5 + vv) * 2 + 1) * 19 + pcl) * 2];
                float sR0, sI0, sR1, sI1;
                if (upar == 0) { sR0 = a0.x - a6.x; sI0 = a0.y - a6.y;
                                 sR1 = b0.x - b6.x; sI1 = b0.y - b6.y; }
                else           { sR0 = a0.x + a6.x; sI0 = a0.y + a6.y;
                                 sR1 = b0.x + b6.x; sI1 = b0.y + b6.y; }
                #pragma unroll
                for (int m = 0; m < 3; ++m) {
                    int u = upar ? (2 * m + 2) : (2 * m + 1);   // 1,3,5 or 2,4,(6 skipped)
                    if (upar == 1 && m == 2) continue;
                    int kk = (u * i) % 12;                      // compile-time twiddle
                    float cu = TWC[kk], su = TWS[kk];
                    FR[m] = fmaf(cu, sR0, fmaf(-su, sI0, FR[m]));
                    FI[m] = fmaf(cu, sI0, fmaf( su, sR0, FI[m]));
                    GR[m] = fmaf(cu, sR1, fmaf(-su, sI1, GR[m]));
                    GI[m] = fmaf(cu, sI1, fmaf( su, sR1, GI[m]));
                }
            }
            #pragma unroll
            for (int m = 0; m < 3; ++m) {
                if (upar == 1 && m == 2) continue;
                int u = upar ? (2 * m + 2) : (2 * m + 1);
                float aI = fast_atan2f(FI[m], FR[m] + 1e-8f);
                float aO = fast_atan2f(GI[m], GR[m] + 1e-8f);
                float mI = sqrtf(FR[m] * FR[m] + FI[m] * FI[m]);
                float mO = sqrtf(GR[m] * GR[m] + GI[m] * GI[m]);
                float ff = (float)(u * (vv + 1)) * 0.04f;
                acc += ff * (fabsf(aO - aI) + fabsf(mO - mI));
            }
        }
        acc *= 1e-4f / 32.f;
    } else {
        // ---- SSIM item: (b, c, tile of 8 output rows) ----
        int idx = grp;                         // 0..1823
        int b    = idx / 57;
        int rem  = idx % 57;
        int c    = rem / 19;
        int tile = rem % 19;
        int r0 = tile * 8;
        const float* px = Pl + (size_t)(b * 3 + c) * PLANE;
        const float* py = px + (size_t)96 * PLANE;

        // vertical 11-tap: 8*40 = 320 tasks
        for (int t = tid; t < 320; t += THREADS) {
            int orow = t / 40;
            int cbase = (t % 40) * 4;
            float ax[4] = {0,0,0,0}, ay[4] = {0,0,0,0};
            float axx[4] = {0,0,0,0}, ayy[4] = {0,0,0,0}, axy[4] = {0,0,0,0};
            #pragma unroll
            for (int kk = 0; kk < 11; ++kk) {
                int row = r0 + orow + kk;
                row = row < 160 ? row : 159;   // clamped rows feed only masked outputs
                float4 qx = *(const float4*)(px + row * 160 + cbase);
                float4 qy = *(const float4*)(py + row * 160 + cbase);
                float wg = GW[kk];
                float xs[4] = {qx.x, qx.y, qx.z, qx.w};
                float ys[4] = {qy.x, qy.y, qy.z, qy.w};
                #pragma unroll
                for (int o = 0; o < 4; ++o) {
                    ax[o]  += wg * xs[o];          ay[o]  += wg * ys[o];
                    axx[o] += wg * (xs[o]*xs[o]);  ayy[o] += wg * (ys[o]*ys[o]);
                    axy[o] += wg * (xs[o]*ys[o]);
                }
            }
            int base = orow * 160 + cbase;
            *(float4*)&SMEM[0 * 1296 + base] = make_float4(ax[0],  ax[1],  ax[2],  ax[3]);
            *(float4*)&SMEM[1 * 1296 + base] = make_float4(ay[0],  ay[1],  ay[2],  ay[3]);
            *(float4*)&SMEM[2 * 1296 + base] = make_float4(axx[0], axx[1], axx[2], axx[3]);
            *(float4*)&SMEM[3 * 1296 + base] = make_float4(ayy[0], ayy[1], ayy[2], ayy[3]);
            *(float4*)&SMEM[4 * 1296 + base] = make_float4(axy[0], axy[1], axy[2], axy[3]);
        }
        __syncthreads();

        // horizontal 11-tap + SSIM: 304 tasks (orow, oc-quad); SCALAR stride-4 LDS reads
        // (lane stride 4 floats = 4-way conflict, vs previous b128 16-way)
        for (int t = tid; t < 304; t += THREADS) {
            int orow = t / 38;
            int ocq = (t % 38) * 4;
            float st[5][4];
            #pragma unroll
            for (int p = 0; p < 5; ++p) {
                float vals[14];
                #pragma unroll
                for (int kk = 0; kk < 14; ++kk)
                    vals[kk] = SMEM[p * 1296 + orow * 160 + ocq + kk];
                #pragma unroll
                for (int o = 0; o < 4; ++o) {
                    float s = 0.f;
                    #pragma unroll
                    for (int kk = 0; kk < 11; ++kk) s += GW[kk] * vals[o + kk];
                    st[p][o] = s;
                }
            }
            const float c1 = 1e-4f, c2 = 9e-4f;
            #pragma unroll
            for (int o = 0; o < 4; ++o) {
                if (r0 + orow < OUT_SZ && ocq + o < OUT_SZ) {
                    float mx = st[0][o], my = st[1][o];
                    float vx = st[2][o] - mx * mx;
                    float vy = st[3][o] - my * my;
                    float cv = st[4][o] - mx * my;
                    float lum = (2.f * mx * my + c1) / (mx * mx + my * my + c1);
                    float cs  = (2.f * cv + c2) / (vx + vy + c2);
                    acc += lum * cs;
                }
            }
        }
        acc *= 1.f / (32.f * 150.f * 150.f * 3.f);
    }

    // block reduce -> one device-scope atomic per block
    #pragma unroll
    for (int o = 32; o > 0; o >>= 1) acc += __shfl_down(acc, o, 64);
    if ((tid & 63) == 0) sm4[tid >> 6] = acc;
    __syncthreads();
    if (tid == 0) atomicAdd(out, sm4[0] + sm4[1] + sm4[2] + sm4[3]);
}

extern "C" void kernel_launch(void* const* d_in, const int* in_sizes, int n_in,
                              void* d_out, int out_size, void* d_ws, size_t ws_size,
                              hipStream_t stream) {
    const float* mean   = (const float*)d_in[0];
    const float* logvar = (const float*)d_in[1];
    const float* xin    = (const float*)d_in[2];
    const float* xout   = (const float*)d_in[3];
    float* out = (float*)d_out;
    float* Pl = (float*)d_ws;                    // 19.7 MB planes (ws proven >= 46.7 MB)

    transpose_kernel<<<1601, 256, 0, stream>>>(xin, xout, mean, logvar, Pl, out);
    work_kernel<<<N_WORK, THREADS, 0, stream>>>(Pl, out);
}

// Round 11
// 142.387 us; speedup vs baseline: 1.1071x; 1.1071x over previous
//
#include <hip/hip_runtime.h>
#include <math.h>

#define BATCH 32
#define NPIX 160
#define LDIM 128
#define OUT_SZ 150        // 160 - 11 + 1
#define PLANE 25600       // 160*160

#define THREADS 512
// fused grid: 32 groups x (57 stft + 30 ssim) = 2784 blocks
#define N_BLOCKS 2784
#define VSTRIDE 2560      // ssim V-plane stride in LDS floats

// e^{-i*2pi*k/12}; entries 0 / ±0.5 / ±0.866 / ±1 -> FMAs fold at compile time
__device__ constexpr float TWC[12] = { 1.f, 0.86602540f, 0.5f, 0.f, -0.5f, -0.86602540f,
                                      -1.f,-0.86602540f,-0.5f, 0.f,  0.5f,  0.86602540f};
__device__ constexpr float TWS[12] = { 0.f,-0.5f,-0.86602540f,-1.f,-0.86602540f,-0.5f,
                                       0.f, 0.5f, 0.86602540f, 1.f, 0.86602540f, 0.5f};

__device__ constexpr float GW[11] = {0.00102838f, 0.00759876f, 0.03600076f, 0.10936070f,
                                     0.21300554f, 0.26601172f, 0.21300554f, 0.10936070f,
                                     0.03600076f, 0.00759876f, 0.00102838f};

// minimax atan poly, max err ~1e-6 rad (validated R7/R9/R10, absmax 0.0)
__device__ __forceinline__ float fast_atan2f(float y, float x) {
    float ax = fabsf(x), ay = fabsf(y);
    float mx = fmaxf(ax, ay), mn = fminf(ax, ay);
    float z = mn / mx;
    float z2 = z * z;
    float p = fmaf(z2, -0.01172120f, 0.05265332f);
    p = fmaf(z2, p, -0.11643287f);
    p = fmaf(z2, p, 0.19354346f);
    p = fmaf(z2, p, -0.33262347f);
    p = fmaf(z2, p, 0.99997726f);
    p = p * z;
    if (ay > ax) p = 1.57079632679489662f - p;
    if (x < 0.f) p = 3.14159265358979323f - p;
    return (y < 0.f) ? -p : p;
}

// ---------------- transpose: NHWC -> planar [img][b][c][row][col]; block 1600 = KLD ----------------
__global__ __launch_bounds__(256) void transpose_kernel(const float* __restrict__ xin,
                                                        const float* __restrict__ xout,
                                                        const float* __restrict__ mean,
                                                        const float* __restrict__ logvar,
                                                        float* __restrict__ Pl,
                                                        float* __restrict__ out) {
    if (blockIdx.x == 1600) {
        float a = 0.f;
        for (int i = threadIdx.x; i < BATCH * LDIM; i += 256) {
            float m = mean[i], lv = logvar[i];
            a += -0.5f * (1.f + lv - expf(lv) - m * m) * (1.f / 32.f);
        }
        #pragma unroll
        for (int o = 32; o > 0; o >>= 1) a += __shfl_down(a, o, 64);
        __shared__ float sm[4];
        if ((threadIdx.x & 63) == 0) sm[threadIdx.x >> 6] = a;
        __syncthreads();
        if (threadIdx.x == 0) out[0] = sm[0] + sm[1] + sm[2] + sm[3];
        return;
    }
    int t = blockIdx.x * 256 + threadIdx.x;
    int colq = t % 40;
    int row  = (t / 40) % 160;
    int b    = (t / 6400) % 32;
    int img  = t / 204800;
    const float* src = img ? xout : xin;
    const float4* q = (const float4*)(src + ((size_t)(b * 160 + row) * 160 + colq * 4) * 3);
    float4 f0 = q[0], f1 = q[1], f2 = q[2];
    float* dst = Pl + (size_t)(img * 96 + b * 3) * PLANE + row * 160 + colq * 4;
    *(float4*)(dst)             = make_float4(f0.x, f0.w, f1.z, f2.y);
    *(float4*)(dst + PLANE)     = make_float4(f0.y, f1.x, f1.w, f2.z);
    *(float4*)(dst + 2 * PLANE) = make_float4(f0.z, f1.y, f2.x, f2.w);
}

// ---------------- fused work kernel (R7 shell + validated upgrades) ----------------
__global__ __launch_bounds__(THREADS) void work_kernel(const float* __restrict__ Pl,
                                                       float* __restrict__ out) {
    __shared__ __align__(16) float SMEM[12800];  // stft RD 12160 fl / ssim V 5*2560 fl
    __shared__ float sm8[8];
    const int tid = threadIdx.x;
    const int gid = blockIdx.x;
    const int grp = gid / 87, k87 = gid % 87;
    float acc = 0.f;

    if (k87 < 57) {
        // ---- STFT role: idx -> (b, c, prg); covers rows 8*prg .. +15, all 38 pc ----
        int idx = grp * 57 + k87;             // 0..1823
        int b   = idx / 57;
        int rem = idx % 57;
        int c   = rem / 19;
        int prg = rem % 19;
        int row0 = prg * 8;
        const float* base0 = Pl + (size_t)(b * 3 + c) * PLANE;
        const float* base1 = base0 + (size_t)96 * PLANE;

        // phase A: 608 tasks (r, pc), each does BOTH images (6 f4 loads -> MLP)
        for (int t = tid; t < 608; t += THREADS) {
            int pc = t % 38;
            int r  = t / 38;
            const float* rp0 = base0 + (row0 + r) * 160 + pc * 4;
            const float* rp1 = base1 + (row0 + r) * 160 + pc * 4;
            float4 p0 = *(const float4*)(rp0);
            float4 p1 = *(const float4*)(rp0 + 4);
            float4 p2 = *(const float4*)(rp0 + 8);
            float4 q0 = *(const float4*)(rp1);
            float4 q1 = *(const float4*)(rp1 + 4);
            float4 q2 = *(const float4*)(rp1 + 8);
            float xa[12] = {p0.x,p0.y,p0.z,p0.w, p1.x,p1.y,p1.z,p1.w, p2.x,p2.y,p2.z,p2.w};
            float xb[12] = {q0.x,q0.y,q0.z,q0.w, q1.x,q1.y,q1.z,q1.w, q2.x,q2.y,q2.z,q2.w};
            #pragma unroll
            for (int img = 0; img < 2; ++img) {
                const float* x = img ? xb : xa;
                float ev[5] = {x[1]+x[11], x[2]+x[10], x[3]+x[9], x[4]+x[8], x[5]+x[7]};
                float ov[5] = {x[1]-x[11], x[2]-x[10], x[3]-x[9], x[4]-x[8], x[5]-x[7]};
                #pragma unroll
                for (int vv = 0; vv < 5; ++vv) {
                    int v = vv + 1;
                    float re = x[0] + ((v & 1) ? -x[6] : x[6]);
                    float im = 0.f;
                    #pragma unroll
                    for (int j = 1; j <= 5; ++j) {
                        int kk = (v * j) % 12;           // compile-time
                        re = fmaf(ev[j-1], TWC[kk], re);
                        im = fmaf(ov[j-1], TWS[kk], im);
                    }
                    // RD[r][vv][img][pc][2]; pc lane-consecutive -> contiguous b64 writes
                    int i2 = (((r * 5 + vv) * 2 + img) * 38 + pc) * 2;
                    *(float2*)&SMEM[i2] = make_float2(re, im);
                }
            }
        }
        __syncthreads();

        // phase B: 760 tasks (g, vv, pc, u-parity); odd u uses sm-fold, even u sp-fold
        for (int t = tid; t < 760; t += THREADS) {
            int pc   = t % 38;
            int vv   = (t / 38) % 5;
            int g    = (t / 190) & 1;
            int upar = t / 380;            // 0: u=1,3,5 ; 1: u=2,4
            float FR[3] = {0,0,0}, FI[3] = {0,0,0};
            float GR[3] = {0,0,0}, GI[3] = {0,0,0};
            #pragma unroll
            for (int i = 0; i < 6; ++i) {
                int rlo = 4 * g + i, rhi = rlo + 6;
                float2 a0 = *(const float2*)&SMEM[(((rlo * 5 + vv) * 2 + 0) * 38 + pc) * 2];
                float2 a6 = *(const float2*)&SMEM[(((rhi * 5 + vv) * 2 + 0) * 38 + pc) * 2];
                float2 b0 = *(const float2*)&SMEM[(((rlo * 5 + vv) * 2 + 1) * 38 + pc) * 2];
                float2 b6 = *(const float2*)&SMEM[(((rhi * 5 + vv) * 2 + 1) * 38 + pc) * 2];
                float sR0, sI0, sR1, sI1;
                if (upar == 0) { sR0 = a0.x - a6.x; sI0 = a0.y - a6.y;
                                 sR1 = b0.x - b6.x; sI1 = b0.y - b6.y; }
                else           { sR0 = a0.x + a6.x; sI0 = a0.y + a6.y;
                                 sR1 = b0.x + b6.x; sI1 = b0.y + b6.y; }
                #pragma unroll
                for (int m = 0; m < 3; ++m) {
                    int u = upar ? (2 * m + 2) : (2 * m + 1);
                    if (upar == 1 && m == 2) continue;
                    int kk = (u * i) % 12;                      // compile-time twiddle
                    float cu = TWC[kk], su = TWS[kk];
                    FR[m] = fmaf(cu, sR0, fmaf(-su, sI0, FR[m]));
                    FI[m] = fmaf(cu, sI0, fmaf( su, sR0, FI[m]));
                    GR[m] = fmaf(cu, sR1, fmaf(-su, sI1, GR[m]));
                    GI[m] = fmaf(cu, sI1, fmaf( su, sR1, GI[m]));
                }
            }
            #pragma unroll
            for (int m = 0; m < 3; ++m) {
                if (upar == 1 && m == 2) continue;
                int u = upar ? (2 * m + 2) : (2 * m + 1);
                float aI = fast_atan2f(FI[m], FR[m] + 1e-8f);
                float aO = fast_atan2f(GI[m], GR[m] + 1e-8f);
                float mI = sqrtf(FR[m] * FR[m] + FI[m] * FI[m]);
                float mO = sqrtf(GR[m] * GR[m] + GI[m] * GI[m]);
                float ff = (float)(u * (vv + 1)) * 0.04f;
                acc += ff * (fabsf(aO - aI) + fabsf(mO - mI));
            }
        }
        acc *= 1e-4f / 32.f;
    } else {
        // ---- SSIM role: idx -> (b, c, 16-row tile) ----
        int idx = grp * 30 + (k87 - 57);      // 0..959
        int b    = idx / 30;
        int rem  = idx % 30;
        int c    = rem / 10;
        int tile = rem % 10;
        int r0 = tile * 16;
        const float* px = Pl + (size_t)(b * 3 + c) * PLANE;
        const float* py = px + (size_t)96 * PLANE;

        // phase V: vertical 11-tap, 16*40 = 640 tasks; contiguous f4 LDS writes (free)
        for (int t = tid; t < 640; t += THREADS) {
            int orow = t / 40;
            int cbase = (t % 40) * 4;
            float ax[4] = {0,0,0,0}, ay[4] = {0,0,0,0};
            float axx[4] = {0,0,0,0}, ayy[4] = {0,0,0,0}, axy[4] = {0,0,0,0};
            #pragma unroll
            for (int kk = 0; kk < 11; ++kk) {
                int row = r0 + orow + kk;
                row = row < 160 ? row : 159;   // clamped rows feed only masked outputs
                float4 qx = *(const float4*)(px + row * 160 + cbase);
                float4 qy = *(const float4*)(py + row * 160 + cbase);
                float wg = GW[kk];
                float xs[4] = {qx.x, qx.y, qx.z, qx.w};
                float ys[4] = {qy.x, qy.y, qy.z, qy.w};
                #pragma unroll
                for (int o = 0; o < 4; ++o) {
                    ax[o]  += wg * xs[o];          ay[o]  += wg * ys[o];
                    axx[o] += wg * (xs[o]*xs[o]);  ayy[o] += wg * (ys[o]*ys[o]);
                    axy[o] += wg * (xs[o]*ys[o]);
                }
            }
            int base = orow * 160 + cbase;
            *(float4*)&SMEM[0 * VSTRIDE + base] = make_float4(ax[0],  ax[1],  ax[2],  ax[3]);
            *(float4*)&SMEM[1 * VSTRIDE + base] = make_float4(ay[0],  ay[1],  ay[2],  ay[3]);
            *(float4*)&SMEM[2 * VSTRIDE + base] = make_float4(axx[0], axx[1], axx[2], axx[3]);
            *(float4*)&SMEM[3 * VSTRIDE + base] = make_float4(ayy[0], ayy[1], ayy[2], ayy[3]);
            *(float4*)&SMEM[4 * VSTRIDE + base] = make_float4(axy[0], axy[1], axy[2], axy[3]);
        }
        __syncthreads();

        // phase H: 16 orows x 75 col-pairs = 1200 tasks, 2 outputs each.
        // Scalar 12-float windows, lane stride 2 floats -> 2-way LDS aliasing (free).
        for (int t = tid; t < 1200; t += THREADS) {
            int orow = t / 75;
            int oc = (t % 75) * 2;
            float st[5][2];
            #pragma unroll
            for (int p = 0; p < 5; ++p) {
                float vals[12];
                #pragma unroll
                for (int kk = 0; kk < 12; ++kk)
                    vals[kk] = SMEM[p * VSTRIDE + orow * 160 + oc + kk];
                float s0 = 0.f, s1 = 0.f;
                #pragma unroll
                for (int kk = 0; kk < 11; ++kk) {
                    s0 += GW[kk] * vals[kk];
                    s1 += GW[kk] * vals[kk + 1];
                }
                st[p][0] = s0; st[p][1] = s1;
            }
            const float c1 = 1e-4f, c2 = 9e-4f;
            if (r0 + orow < OUT_SZ) {
                #pragma unroll
                for (int o = 0; o < 2; ++o) {
                    float mx = st[0][o], my = st[1][o];
                    float vx = st[2][o] - mx * mx;
                    float vy = st[3][o] - my * my;
                    float cv = st[4][o] - mx * my;
                    float lum = (2.f * mx * my + c1) / (mx * mx + my * my + c1);
                    float cs  = (2.f * cv + c2) / (vx + vy + c2);
                    acc += lum * cs;
                }
            }
        }
        acc *= 1.f / (32.f * 150.f * 150.f * 3.f);
    }

    // block reduce (8 waves) -> one device-scope atomic per block
    #pragma unroll
    for (int o = 32; o > 0; o >>= 1) acc += __shfl_down(acc, o, 64);
    if ((tid & 63) == 0) sm8[tid >> 6] = acc;
    __syncthreads();
    if (tid == 0) {
        float s = sm8[0];
        #pragma unroll
        for (int i = 1; i < 8; ++i) s += sm8[i];
        atomicAdd(out, s);
    }
}

extern "C" void kernel_launch(void* const* d_in, const int* in_sizes, int n_in,
                              void* d_out, int out_size, void* d_ws, size_t ws_size,
                              hipStream_t stream) {
    const float* mean   = (const float*)d_in[0];
    const float* logvar = (const float*)d_in[1];
    const float* xin    = (const float*)d_in[2];
    const float* xout   = (const float*)d_in[3];
    float* out = (float*)d_out;
    float* Pl = (float*)d_ws;                    // 19.7 MB planes (ws proven >= 46.7 MB)

    transpose_kernel<<<1601, 256, 0, stream>>>(xin, xout, mean, logvar, Pl, out);
    work_kernel<<<N_BLOCKS, THREADS, 0, stream>>>(Pl, out);
}

// Round 12
// 133.780 us; speedup vs baseline: 1.1784x; 1.0643x over previous
//
#include <hip/hip_runtime.h>
#include <math.h>

#define BATCH 32
#define NPIX 160
#define LDIM 128
#define OUT_SZ 150        // 160 - 11 + 1
#define PLANE 25600       // 160*160

#define THREADS 512
// fused grid: 32 groups x (57 stft + 57 ssim) = 3648 blocks
#define N_BLOCKS 3648
// ssim LDS carve: stage sx/sy = 2*18*160 = 5760 fl, then V planes 5*1296 fl
#define SSIM_V_OFF 5760
#define VSTRIDE 1296

// e^{-i*2pi*k/12}; entries 0 / ±0.5 / ±0.866 / ±1 -> FMAs fold at compile time
__device__ constexpr float TWC[12] = { 1.f, 0.86602540f, 0.5f, 0.f, -0.5f, -0.86602540f,
                                      -1.f,-0.86602540f,-0.5f, 0.f,  0.5f,  0.86602540f};
__device__ constexpr float TWS[12] = { 0.f,-0.5f,-0.86602540f,-1.f,-0.86602540f,-0.5f,
                                       0.f, 0.5f, 0.86602540f, 1.f, 0.86602540f, 0.5f};

__device__ constexpr float GW[11] = {0.00102838f, 0.00759876f, 0.03600076f, 0.10936070f,
                                     0.21300554f, 0.26601172f, 0.21300554f, 0.10936070f,
                                     0.03600076f, 0.00759876f, 0.00102838f};

// minimax atan poly, max err ~1e-6 rad (validated R7/R9-R11, absmax 0.0)
__device__ __forceinline__ float fast_atan2f(float y, float x) {
    float ax = fabsf(x), ay = fabsf(y);
    float mx = fmaxf(ax, ay), mn = fminf(ax, ay);
    float z = mn / mx;
    float z2 = z * z;
    float p = fmaf(z2, -0.01172120f, 0.05265332f);
    p = fmaf(z2, p, -0.11643287f);
    p = fmaf(z2, p, 0.19354346f);
    p = fmaf(z2, p, -0.33262347f);
    p = fmaf(z2, p, 0.99997726f);
    p = p * z;
    if (ay > ax) p = 1.57079632679489662f - p;
    if (x < 0.f) p = 3.14159265358979323f - p;
    return (y < 0.f) ? -p : p;
}

// ---------------- transpose: NHWC -> planar [img][b][c][row][col]; block 1600 = KLD ----------------
__global__ __launch_bounds__(256) void transpose_kernel(const float* __restrict__ xin,
                                                        const float* __restrict__ xout,
                                                        const float* __restrict__ mean,
                                                        const float* __restrict__ logvar,
                                                        float* __restrict__ Pl,
                                                        float* __restrict__ out) {
    if (blockIdx.x == 1600) {
        float a = 0.f;
        for (int i = threadIdx.x; i < BATCH * LDIM; i += 256) {
            float m = mean[i], lv = logvar[i];
            a += -0.5f * (1.f + lv - expf(lv) - m * m) * (1.f / 32.f);
        }
        #pragma unroll
        for (int o = 32; o > 0; o >>= 1) a += __shfl_down(a, o, 64);
        __shared__ float sm[4];
        if ((threadIdx.x & 63) == 0) sm[threadIdx.x >> 6] = a;
        __syncthreads();
        if (threadIdx.x == 0) out[0] = sm[0] + sm[1] + sm[2] + sm[3];
        return;
    }
    int t = blockIdx.x * 256 + threadIdx.x;
    int colq = t % 40;
    int row  = (t / 40) % 160;
    int b    = (t / 6400) % 32;
    int img  = t / 204800;
    const float* src = img ? xout : xin;
    const float4* q = (const float4*)(src + ((size_t)(b * 160 + row) * 160 + colq * 4) * 3);
    float4 f0 = q[0], f1 = q[1], f2 = q[2];
    float* dst = Pl + (size_t)(img * 96 + b * 3) * PLANE + row * 160 + colq * 4;
    *(float4*)(dst)             = make_float4(f0.x, f0.w, f1.z, f2.y);
    *(float4*)(dst + PLANE)     = make_float4(f0.y, f1.x, f1.w, f2.z);
    *(float4*)(dst + 2 * PLANE) = make_float4(f0.z, f1.y, f2.x, f2.w);
}

// ---------------- fused work kernel: 57 stft + 57 ssim per group ----------------
__global__ __launch_bounds__(THREADS) void work_kernel(const float* __restrict__ Pl,
                                                       float* __restrict__ out) {
    __shared__ __align__(16) float SMEM[12256];  // stft RD 12160 fl / ssim 5760+6480 fl
    __shared__ float sm8[8];
    const int tid = threadIdx.x;
    const int gid = blockIdx.x;
    const int grp = gid / 114, k = gid % 114;
    float acc = 0.f;

    if (k < 57) {
        // ---- STFT role (R7-verbatim structure, measured 68 us shell) ----
        int idx = grp * 57 + k;               // 0..1823
        int b   = idx / 57;
        int rem = idx % 57;
        int c   = rem / 19;
        int prg = rem % 19;
        int row0 = prg * 8;
        const float* base0 = Pl + (size_t)(b * 3 + c) * PLANE;
        const float* base1 = base0 + (size_t)96 * PLANE;

        // phase A: 1216 tasks (img, r, pc), one image each; real-input symmetry
        for (int t = tid; t < 1216; t += THREADS) {
            int pc  = t % 38;
            int r   = (t / 38) % 16;
            int img = t / 608;
            const float* rp = (img ? base1 : base0) + (row0 + r) * 160 + pc * 4;
            float4 q0 = *(const float4*)(rp);
            float4 q1 = *(const float4*)(rp + 4);
            float4 q2 = *(const float4*)(rp + 8);
            float x[12] = {q0.x,q0.y,q0.z,q0.w, q1.x,q1.y,q1.z,q1.w, q2.x,q2.y,q2.z,q2.w};
            float ev[5] = {x[1]+x[11], x[2]+x[10], x[3]+x[9], x[4]+x[8], x[5]+x[7]};
            float ov[5] = {x[1]-x[11], x[2]-x[10], x[3]-x[9], x[4]-x[8], x[5]-x[7]};
            #pragma unroll
            for (int vv = 0; vv < 5; ++vv) {
                int v = vv + 1;
                float re = x[0] + ((v & 1) ? -x[6] : x[6]);
                float im = 0.f;
                #pragma unroll
                for (int j = 1; j <= 5; ++j) {
                    int kk = (v * j) % 12;           // compile-time
                    re = fmaf(ev[j-1], TWC[kk], re);
                    im = fmaf(ov[j-1], TWS[kk], im);
                }
                // RD[r][vv][img][pc][2]; pc lane-consecutive -> contiguous b64 writes
                int i2 = (((r * 5 + vv) * 2 + img) * 38 + pc) * 2;
                *(float2*)&SMEM[i2] = make_float2(re, im);
            }
        }
        __syncthreads();

        // phase B: 380 tasks (g, vv, pc), all 5 u per task; half-period fold
        if (tid < 380) {
            int pc = tid % 38;
            int vv = (tid / 38) % 5;
            int g  = tid / 190;
            float FR0[5] = {0,0,0,0,0}, FI0[5] = {0,0,0,0,0};
            float FR1[5] = {0,0,0,0,0}, FI1[5] = {0,0,0,0,0};
            #pragma unroll
            for (int i = 0; i < 6; ++i) {
                int rlo = 4 * g + i, rhi = rlo + 6;
                float2 a0 = *(const float2*)&SMEM[(((rlo * 5 + vv) * 2 + 0) * 38 + pc) * 2];
                float2 a6 = *(const float2*)&SMEM[(((rhi * 5 + vv) * 2 + 0) * 38 + pc) * 2];
                float2 b0 = *(const float2*)&SMEM[(((rlo * 5 + vv) * 2 + 1) * 38 + pc) * 2];
                float2 b6 = *(const float2*)&SMEM[(((rhi * 5 + vv) * 2 + 1) * 38 + pc) * 2];
                float spR0 = a0.x + a6.x, spI0 = a0.y + a6.y;
                float smR0 = a0.x - a6.x, smI0 = a0.y - a6.y;
                float spR1 = b0.x + b6.x, spI1 = b0.y + b6.y;
                float smR1 = b0.x - b6.x, smI1 = b0.y - b6.y;
                #pragma unroll
                for (int uu = 0; uu < 5; ++uu) {
                    int u = uu + 1;
                    int kk = (u * i) % 12;           // compile-time twiddle
                    float cu = TWC[kk], su = TWS[kk];
                    float sR0 = (u & 1) ? smR0 : spR0, sI0 = (u & 1) ? smI0 : spI0;
                    float sR1 = (u & 1) ? smR1 : spR1, sI1 = (u & 1) ? smI1 : spI1;
                    FR0[uu] = fmaf(cu, sR0, fmaf(-su, sI0, FR0[uu]));
                    FI0[uu] = fmaf(cu, sI0, fmaf( su, sR0, FI0[uu]));
                    FR1[uu] = fmaf(cu, sR1, fmaf(-su, sI1, FR1[uu]));
                    FI1[uu] = fmaf(cu, sI1, fmaf( su, sR1, FI1[uu]));
                }
            }
            #pragma unroll
            for (int uu = 0; uu < 5; ++uu) {
                float aI = fast_atan2f(FI0[uu], FR0[uu] + 1e-8f);
                float aO = fast_atan2f(FI1[uu], FR1[uu] + 1e-8f);
                float mI = sqrtf(FR0[uu] * FR0[uu] + FI0[uu] * FI0[uu]);
                float mO = sqrtf(FR1[uu] * FR1[uu] + FI1[uu] * FI1[uu]);
                float ff = (float)((uu + 1) * (vv + 1)) * 0.04f;
                acc += ff * (fabsf(aO - aI) + fabsf(mO - mI));
            }
        }
        acc *= 1e-4f / 32.f;
    } else {
        // ---- SSIM role: (b, c, 8-row tile); LDS-staged input (bulk coalesced) ----
        int idx = grp * 57 + (k - 57);        // 0..1823
        int b    = idx / 57;
        int rem  = idx % 57;
        int c    = rem / 19;
        int tile = rem % 19;
        int r0 = tile * 8;
        const float* px = Pl + (size_t)(b * 3 + c) * PLANE;
        const float* py = px + (size_t)96 * PLANE;

        // stage rows r0..r0+17 for both images: 1440 float4 tasks, flat & coalesced
        for (int t = tid; t < 1440; t += THREADS) {
            int img = t / 720;
            int rr  = (t % 720) / 40;          // 0..17
            int cq  = (t % 40) * 4;
            int row = r0 + rr;
            float4 v = make_float4(0.f, 0.f, 0.f, 0.f);
            if (row < NPIX) v = *(const float4*)((img ? py : px) + row * 160 + cq);
            *(float4*)&SMEM[(img * 18 + rr) * 160 + cq] = v;
        }
        __syncthreads();

        // phase V: vertical 11-tap from LDS, 320 tasks (orow, colq)
        for (int t = tid; t < 320; t += THREADS) {
            int orow = t / 40;
            int cbase = (t % 40) * 4;
            float ax[4] = {0,0,0,0}, ay[4] = {0,0,0,0};
            float axx[4] = {0,0,0,0}, ayy[4] = {0,0,0,0}, axy[4] = {0,0,0,0};
            #pragma unroll
            for (int kk = 0; kk < 11; ++kk) {
                float4 qx = *(const float4*)&SMEM[(orow + kk) * 160 + cbase];
                float4 qy = *(const float4*)&SMEM[(18 + orow + kk) * 160 + cbase];
                float wg = GW[kk];
                float xs[4] = {qx.x, qx.y, qx.z, qx.w};
                float ys[4] = {qy.x, qy.y, qy.z, qy.w};
                #pragma unroll
                for (int o = 0; o < 4; ++o) {
                    ax[o]  += wg * xs[o];          ay[o]  += wg * ys[o];
                    axx[o] += wg * (xs[o]*xs[o]);  ayy[o] += wg * (ys[o]*ys[o]);
                    axy[o] += wg * (xs[o]*ys[o]);
                }
            }
            int base = SSIM_V_OFF + orow * 160 + cbase;
            *(float4*)&SMEM[base + 0 * VSTRIDE * 0] = make_float4(ax[0], ax[1], ax[2], ax[3]);
            // (separate planes below; first write above is plane 0)
            *(float4*)&SMEM[SSIM_V_OFF + 1 * VSTRIDE + orow * 160 + cbase] = make_float4(ay[0],  ay[1],  ay[2],  ay[3]);
            *(float4*)&SMEM[SSIM_V_OFF + 2 * VSTRIDE + orow * 160 + cbase] = make_float4(axx[0], axx[1], axx[2], axx[3]);
            *(float4*)&SMEM[SSIM_V_OFF + 3 * VSTRIDE + orow * 160 + cbase] = make_float4(ayy[0], ayy[1], ayy[2], ayy[3]);
            *(float4*)&SMEM[SSIM_V_OFF + 4 * VSTRIDE + orow * 160 + cbase] = make_float4(axy[0], axy[1], axy[2], axy[3]);
        }
        __syncthreads();

        // phase H: 600 tasks (8 orows x 75 col-pairs), stride-2 scalar windows (2-way, free)
        for (int t = tid; t < 600; t += THREADS) {
            int orow = t / 75;
            int oc = (t % 75) * 2;
            float st[5][2];
            #pragma unroll
            for (int p = 0; p < 5; ++p) {
                float vals[12];
                #pragma unroll
                for (int kk = 0; kk < 12; ++kk)
                    vals[kk] = SMEM[SSIM_V_OFF + p * VSTRIDE + orow * 160 + oc + kk];
                float s0 = 0.f, s1 = 0.f;
                #pragma unroll
                for (int kk = 0; kk < 11; ++kk) {
                    s0 += GW[kk] * vals[kk];
                    s1 += GW[kk] * vals[kk + 1];
                }
                st[p][0] = s0; st[p][1] = s1;
            }
            const float c1 = 1e-4f, c2 = 9e-4f;
            if (r0 + orow < OUT_SZ) {
                #pragma unroll
                for (int o = 0; o < 2; ++o) {
                    float mx = st[0][o], my = st[1][o];
                    float vx = st[2][o] - mx * mx;
                    float vy = st[3][o] - my * my;
                    float cv = st[4][o] - mx * my;
                    float lum = (2.f * mx * my + c1) / (mx * mx + my * my + c1);
                    float cs  = (2.f * cv + c2) / (vx + vy + c2);
                    acc += lum * cs;
                }
            }
        }
        acc *= 1.f / (32.f * 150.f * 150.f * 3.f);
    }

    // block reduce (8 waves) -> one device-scope atomic per block
    #pragma unroll
    for (int o = 32; o > 0; o >>= 1) acc += __shfl_down(acc, o, 64);
    if ((tid & 63) == 0) sm8[tid >> 6] = acc;
    __syncthreads();
    if (tid == 0) {
        float s = sm8[0];
        #pragma unroll
        for (int i = 1; i < 8; ++i) s += sm8[i];
        atomicAdd(out, s);
    }
}

extern "C" void kernel_launch(void* const* d_in, const int* in_sizes, int n_in,
                              void* d_out, int out_size, void* d_ws, size_t ws_size,
                              hipStream_t stream) {
    const float* mean   = (const float*)d_in[0];
    const float* logvar = (const float*)d_in[1];
    const float* xin    = (const float*)d_in[2];
    const float* xout   = (const float*)d_in[3];
    float* out = (float*)d_out;
    float* Pl = (float*)d_ws;                    // 19.7 MB planes (ws proven >= 46.7 MB)

    transpose_kernel<<<1601, 256, 0, stream>>>(xin, xout, mean, logvar, Pl, out);
    work_kernel<<<N_BLOCKS, THREADS, 0, stream>>>(Pl, out);
}

// Round 13
// 133.179 us; speedup vs baseline: 1.1837x; 1.0045x over previous
//
#include <hip/hip_runtime.h>
#include <hip/hip_fp16.h>
#include <math.h>

#define BATCH 32
#define NPIX 160
#define LDIM 128
#define OUT_SZ 150        // 160 - 11 + 1
#define PLANE 25600       // 160*160

#define THREADS 512
// fused grid: 32 groups x (57 stft + 57 ssim) = 3648 blocks
#define N_BLOCKS 3648
// LDS carve (in float units of SMEM):
//   stft: RD = 6080 half2 = 6080 fl-equiv (24.3 KB)
//   ssim: rows = 18*160 half2 = 2880 fl-equiv; V planes fp32 at offset 2880, 5*1296 fl
#define SSIM_V_OFF 2880
#define VSTRIDE 1296
#define SMEM_FLOATS 9360   // 37.4 KB -> 4 blocks/CU

// e^{-i*2pi*k/12}; entries 0 / ±0.5 / ±0.866 / ±1 -> FMAs fold at compile time
__device__ constexpr float TWC[12] = { 1.f, 0.86602540f, 0.5f, 0.f, -0.5f, -0.86602540f,
                                      -1.f,-0.86602540f,-0.5f, 0.f,  0.5f,  0.86602540f};
__device__ constexpr float TWS[12] = { 0.f,-0.5f,-0.86602540f,-1.f,-0.86602540f,-0.5f,
                                       0.f, 0.5f, 0.86602540f, 1.f, 0.86602540f, 0.5f};

__device__ constexpr float GW[11] = {0.00102838f, 0.00759876f, 0.03600076f, 0.10936070f,
                                     0.21300554f, 0.26601172f, 0.21300554f, 0.10936070f,
                                     0.03600076f, 0.00759876f, 0.00102838f};

// minimax atan poly, max err ~1e-6 rad (validated R7/R9-R12, absmax 0.0)
__device__ __forceinline__ float fast_atan2f(float y, float x) {
    float ax = fabsf(x), ay = fabsf(y);
    float mx = fmaxf(ax, ay), mn = fminf(ax, ay);
    float z = mn / mx;
    float z2 = z * z;
    float p = fmaf(z2, -0.01172120f, 0.05265332f);
    p = fmaf(z2, p, -0.11643287f);
    p = fmaf(z2, p, 0.19354346f);
    p = fmaf(z2, p, -0.33262347f);
    p = fmaf(z2, p, 0.99997726f);
    p = p * z;
    if (ay > ax) p = 1.57079632679489662f - p;
    if (x < 0.f) p = 3.14159265358979323f - p;
    return (y < 0.f) ? -p : p;
}

// ---------------- transpose: NHWC -> planar [img][b][c][row][col]; block 1600 = KLD ----------------
__global__ __launch_bounds__(256) void transpose_kernel(const float* __restrict__ xin,
                                                        const float* __restrict__ xout,
                                                        const float* __restrict__ mean,
                                                        const float* __restrict__ logvar,
                                                        float* __restrict__ Pl,
                                                        float* __restrict__ out) {
    if (blockIdx.x == 1600) {
        float a = 0.f;
        for (int i = threadIdx.x; i < BATCH * LDIM; i += 256) {
            float m = mean[i], lv = logvar[i];
            a += -0.5f * (1.f + lv - expf(lv) - m * m) * (1.f / 32.f);
        }
        #pragma unroll
        for (int o = 32; o > 0; o >>= 1) a += __shfl_down(a, o, 64);
        __shared__ float sm[4];
        if ((threadIdx.x & 63) == 0) sm[threadIdx.x >> 6] = a;
        __syncthreads();
        if (threadIdx.x == 0) out[0] = sm[0] + sm[1] + sm[2] + sm[3];
        return;
    }
    int t = blockIdx.x * 256 + threadIdx.x;
    int colq = t % 40;
    int row  = (t / 40) % 160;
    int b    = (t / 6400) % 32;
    int img  = t / 204800;
    const float* src = img ? xout : xin;
    const float4* q = (const float4*)(src + ((size_t)(b * 160 + row) * 160 + colq * 4) * 3);
    float4 f0 = q[0], f1 = q[1], f2 = q[2];
    float* dst = Pl + (size_t)(img * 96 + b * 3) * PLANE + row * 160 + colq * 4;
    *(float4*)(dst)             = make_float4(f0.x, f0.w, f1.z, f2.y);
    *(float4*)(dst + PLANE)     = make_float4(f0.y, f1.x, f1.w, f2.z);
    *(float4*)(dst + 2 * PLANE) = make_float4(f0.z, f1.y, f2.x, f2.w);
}

// ---------------- fused work kernel: 57 stft + 57 ssim per group ----------------
__global__ __launch_bounds__(THREADS) void work_kernel(const float* __restrict__ Pl,
                                                       float* __restrict__ out) {
    __shared__ __align__(16) float SMEM[SMEM_FLOATS];
    __shared__ float sm8[8];
    const int tid = threadIdx.x;
    const int gid = blockIdx.x;
    const int grp = gid / 114, k = gid % 114;
    float acc = 0.f;

    if (k < 57) {
        // ---- STFT role: (b, c, prg); rows 8*prg..+15, all 38 pc; RD in fp16 ----
        int idx = grp * 57 + k;               // 0..1823
        int b   = idx / 57;
        int rem = idx % 57;
        int c   = rem / 19;
        int prg = rem % 19;
        int row0 = prg * 8;
        const float* base0 = Pl + (size_t)(b * 3 + c) * PLANE;
        const float* base1 = base0 + (size_t)96 * PLANE;
        __half2* RD = (__half2*)SMEM;         // [r][vv][img][pc] -> half2(re, im)

        // phase A: 1216 tasks (img, r, pc); real-input symmetry
        for (int t = tid; t < 1216; t += THREADS) {
            int pc  = t % 38;
            int r   = (t / 38) % 16;
            int img = t / 608;
            const float* rp = (img ? base1 : base0) + (row0 + r) * 160 + pc * 4;
            float4 q0 = *(const float4*)(rp);
            float4 q1 = *(const float4*)(rp + 4);
            float4 q2 = *(const float4*)(rp + 8);
            float x[12] = {q0.x,q0.y,q0.z,q0.w, q1.x,q1.y,q1.z,q1.w, q2.x,q2.y,q2.z,q2.w};
            float ev[5] = {x[1]+x[11], x[2]+x[10], x[3]+x[9], x[4]+x[8], x[5]+x[7]};
            float ov[5] = {x[1]-x[11], x[2]-x[10], x[3]-x[9], x[4]-x[8], x[5]-x[7]};
            #pragma unroll
            for (int vv = 0; vv < 5; ++vv) {
                int v = vv + 1;
                float re = x[0] + ((v & 1) ? -x[6] : x[6]);
                float im = 0.f;
                #pragma unroll
                for (int j = 1; j <= 5; ++j) {
                    int kk = (v * j) % 12;           // compile-time
                    re = fmaf(ev[j-1], TWC[kk], re);
                    im = fmaf(ov[j-1], TWS[kk], im);
                }
                // pc lane-consecutive 4B stores -> conflict-free
                RD[((r * 5 + vv) * 2 + img) * 38 + pc] = __floats2half2_rn(re, im);
            }
        }
        __syncthreads();

        // phase B: 380 tasks (g, vv, pc), all 5 u per task; half-period fold
        if (tid < 380) {
            int pc = tid % 38;
            int vv = (tid / 38) % 5;
            int g  = tid / 190;
            float FR0[5] = {0,0,0,0,0}, FI0[5] = {0,0,0,0,0};
            float FR1[5] = {0,0,0,0,0}, FI1[5] = {0,0,0,0,0};
            #pragma unroll
            for (int i = 0; i < 6; ++i) {
                int rlo = 4 * g + i, rhi = rlo + 6;
                float2 a0 = __half22float2(RD[((rlo * 5 + vv) * 2 + 0) * 38 + pc]);
                float2 a6 = __half22float2(RD[((rhi * 5 + vv) * 2 + 0) * 38 + pc]);
                float2 b0 = __half22float2(RD[((rlo * 5 + vv) * 2 + 1) * 38 + pc]);
                float2 b6 = __half22float2(RD[((rhi * 5 + vv) * 2 + 1) * 38 + pc]);
                float spR0 = a0.x + a6.x, spI0 = a0.y + a6.y;
                float smR0 = a0.x - a6.x, smI0 = a0.y - a6.y;
                float spR1 = b0.x + b6.x, spI1 = b0.y + b6.y;
                float smR1 = b0.x - b6.x, smI1 = b0.y - b6.y;
                #pragma unroll
                for (int uu = 0; uu < 5; ++uu) {
                    int u = uu + 1;
                    int kk = (u * i) % 12;           // compile-time twiddle
                    float cu = TWC[kk], su = TWS[kk];
                    float sR0 = (u & 1) ? smR0 : spR0, sI0 = (u & 1) ? smI0 : spI0;
                    float sR1 = (u & 1) ? smR1 : spR1, sI1 = (u & 1) ? smI1 : spI1;
                    FR0[uu] = fmaf(cu, sR0, fmaf(-su, sI0, FR0[uu]));
                    FI0[uu] = fmaf(cu, sI0, fmaf( su, sR0, FI0[uu]));
                    FR1[uu] = fmaf(cu, sR1, fmaf(-su, sI1, FR1[uu]));
                    FI1[uu] = fmaf(cu, sI1, fmaf( su, sR1, FI1[uu]));
                }
            }
            #pragma unroll
            for (int uu = 0; uu < 5; ++uu) {
                float aI = fast_atan2f(FI0[uu], FR0[uu] + 1e-8f);
                float aO = fast_atan2f(FI1[uu], FR1[uu] + 1e-8f);
                float mI = sqrtf(FR0[uu] * FR0[uu] + FI0[uu] * FI0[uu]);
                float mO = sqrtf(FR1[uu] * FR1[uu] + FI1[uu] * FI1[uu]);
                float ff = (float)((uu + 1) * (vv + 1)) * 0.04f;
                acc += ff * (fabsf(aO - aI) + fabsf(mO - mI));
            }
        }
        acc *= 1e-4f / 32.f;
    } else {
        // ---- SSIM role: (b, c, 8-row tile); rows staged as half2(x,y) pairs ----
        int idx = grp * 57 + (k - 57);        // 0..1823
        int b    = idx / 57;
        int rem  = idx % 57;
        int c    = rem / 19;
        int tile = rem % 19;
        int r0 = tile * 8;
        const float* px = Pl + (size_t)(b * 3 + c) * PLANE;
        const float* py = px + (size_t)96 * PLANE;
        __half2* HXY = (__half2*)SMEM;        // [row][col] -> half2(x, y)

        // stage rows r0..r0+17, both images fused: 720 tasks, b128 LDS writes
        for (int t = tid; t < 720; t += THREADS) {
            int rr = t / 40;                   // 0..17
            int cq = (t % 40) * 4;
            int row = r0 + rr;
            float4 vx = make_float4(0.f, 0.f, 0.f, 0.f);
            float4 vy = make_float4(0.f, 0.f, 0.f, 0.f);
            if (row < NPIX) {
                vx = *(const float4*)(px + row * 160 + cq);
                vy = *(const float4*)(py + row * 160 + cq);
            }
            __half2 h[4] __attribute__((aligned(16)));
            h[0] = __floats2half2_rn(vx.x, vy.x);
            h[1] = __floats2half2_rn(vx.y, vy.y);
            h[2] = __floats2half2_rn(vx.z, vy.z);
            h[3] = __floats2half2_rn(vx.w, vy.w);
            *(float4*)&HXY[rr * 160 + cq] = *(float4*)h;
        }
        __syncthreads();

        // phase V: vertical 11-tap, 320 tasks; 11 b128 reads/task (4 cols x both imgs)
        for (int t = tid; t < 320; t += THREADS) {
            int orow = t / 40;
            int cbase = (t % 40) * 4;
            float ax[4] = {0,0,0,0}, ay[4] = {0,0,0,0};
            float axx[4] = {0,0,0,0}, ayy[4] = {0,0,0,0}, axy[4] = {0,0,0,0};
            #pragma unroll
            for (int kk = 0; kk < 11; ++kk) {
                float4 raw = *(const float4*)&HXY[(orow + kk) * 160 + cbase];
                const __half2* hp = (const __half2*)&raw;
                float wg = GW[kk];
                #pragma unroll
                for (int o = 0; o < 4; ++o) {
                    float2 xy = __half22float2(hp[o]);
                    ax[o]  += wg * xy.x;          ay[o]  += wg * xy.y;
                    axx[o] += wg * (xy.x * xy.x); ayy[o] += wg * (xy.y * xy.y);
                    axy[o] += wg * (xy.x * xy.y);
                }
            }
            int base = SSIM_V_OFF + orow * 160 + cbase;
            *(float4*)&SMEM[base + 0 * VSTRIDE] = make_float4(ax[0],  ax[1],  ax[2],  ax[3]);
            *(float4*)&SMEM[base + 1 * VSTRIDE] = make_float4(ay[0],  ay[1],  ay[2],  ay[3]);
            *(float4*)&SMEM[base + 2 * VSTRIDE] = make_float4(axx[0], axx[1], axx[2], axx[3]);
            *(float4*)&SMEM[base + 3 * VSTRIDE] = make_float4(ayy[0], ayy[1], ayy[2], ayy[3]);
            *(float4*)&SMEM[base + 4 * VSTRIDE] = make_float4(axy[0], axy[1], axy[2], axy[3]);
        }
        __syncthreads();

        // phase H: 600 tasks (8 orows x 75 col-pairs), stride-2 scalar windows (2-way, free)
        for (int t = tid; t < 600; t += THREADS) {
            int orow = t / 75;
            int oc = (t % 75) * 2;
            float st[5][2];
            #pragma unroll
            for (int p = 0; p < 5; ++p) {
                float vals[12];
                #pragma unroll
                for (int kk = 0; kk < 12; ++kk)
                    vals[kk] = SMEM[SSIM_V_OFF + p * VSTRIDE + orow * 160 + oc + kk];
                float s0 = 0.f, s1 = 0.f;
                #pragma unroll
                for (int kk = 0; kk < 11; ++kk) {
                    s0 += GW[kk] * vals[kk];
                    s1 += GW[kk] * vals[kk + 1];
                }
                st[p][0] = s0; st[p][1] = s1;
            }
            const float c1 = 1e-4f, c2 = 9e-4f;
            if (r0 + orow < OUT_SZ) {
                #pragma unroll
                for (int o = 0; o < 2; ++o) {
                    float mx = st[0][o], my = st[1][o];
                    float vx = st[2][o] - mx * mx;
                    float vy = st[3][o] - my * my;
                    float cv = st[4][o] - mx * my;
                    float lum = (2.f * mx * my + c1) / (mx * mx + my * my + c1);
                    float cs  = (2.f * cv + c2) / (vx + vy + c2);
                    acc += lum * cs;
                }
            }
        }
        acc *= 1.f / (32.f * 150.f * 150.f * 3.f);
    }

    // block reduce (8 waves) -> one device-scope atomic per block
    #pragma unroll
    for (int o = 32; o > 0; o >>= 1) acc += __shfl_down(acc, o, 64);
    if ((tid & 63) == 0) sm8[tid >> 6] = acc;
    __syncthreads();
    if (tid == 0) {
        float s = sm8[0];
        #pragma unroll
        for (int i = 1; i < 8; ++i) s += sm8[i];
        atomicAdd(out, s);
    }
}

extern "C" void kernel_launch(void* const* d_in, const int* in_sizes, int n_in,
                              void* d_out, int out_size, void* d_ws, size_t ws_size,
                              hipStream_t stream) {
    const float* mean   = (const float*)d_in[0];
    const float* logvar = (const float*)d_in[1];
    const float* xin    = (const float*)d_in[2];
    const float* xout   = (const float*)d_in[3];
    float* out = (float*)d_out;
    float* Pl = (float*)d_ws;                    // 19.7 MB planes (ws proven >= 46.7 MB)

    transpose_kernel<<<1601, 256, 0, stream>>>(xin, xout, mean, logvar, Pl, out);
    work_kernel<<<N_BLOCKS, THREADS, 0, stream>>>(Pl, out);
}

// Round 14
// 128.463 us; speedup vs baseline: 1.2271x; 1.0367x over previous
//
#include <hip/hip_runtime.h>
#include <hip/hip_fp16.h>
#include <math.h>

#define BATCH 32
#define NPIX 160
#define LDIM 128
#define OUT_SZ 150        // 160 - 11 + 1
#define PLANE 25600

#define THREADS 512
// 32 groups x (57 stft + 57 ssim) = 3648 work blocks + 1 KLD block
#define N_BLOCKS 3649
// LDS carve (float units):
//  stft: stage 16x160 half2 = 2560 fl, RD 6080 half2 = 3040 fl at offset 2560 (total 5600)
//  ssim: stage 18x160 half2 = 2880 fl, V planes fp32 5*1296 at offset 2880 (total 9360)
#define STFT_RD_OFF 2560
#define SSIM_V_OFF 2880
#define VSTRIDE 1296
#define SMEM_FLOATS 9360   // 37.4 KB -> 4 blocks/CU

// e^{-i*2pi*k/12}; entries 0 / ±0.5 / ±0.866 / ±1 -> FMAs fold at compile time
__device__ constexpr float TWC[12] = { 1.f, 0.86602540f, 0.5f, 0.f, -0.5f, -0.86602540f,
                                      -1.f,-0.86602540f,-0.5f, 0.f,  0.5f,  0.86602540f};
__device__ constexpr float TWS[12] = { 0.f,-0.5f,-0.86602540f,-1.f,-0.86602540f,-0.5f,
                                       0.f, 0.5f, 0.86602540f, 1.f, 0.86602540f, 0.5f};

__device__ constexpr float GW[11] = {0.00102838f, 0.00759876f, 0.03600076f, 0.10936070f,
                                     0.21300554f, 0.26601172f, 0.21300554f, 0.10936070f,
                                     0.03600076f, 0.00759876f, 0.00102838f};

// minimax atan poly, max err ~1e-6 rad (validated R7/R9-R13, absmax 0.0)
__device__ __forceinline__ float fast_atan2f(float y, float x) {
    float ax = fabsf(x), ay = fabsf(y);
    float mx = fmaxf(ax, ay), mn = fminf(ax, ay);
    float z = mn / mx;
    float z2 = z * z;
    float p = fmaf(z2, -0.01172120f, 0.05265332f);
    p = fmaf(z2, p, -0.11643287f);
    p = fmaf(z2, p, 0.19354346f);
    p = fmaf(z2, p, -0.33262347f);
    p = fmaf(z2, p, 0.99997726f);
    p = p * z;
    if (ay > ax) p = 1.57079632679489662f - p;
    if (x < 0.f) p = 3.14159265358979323f - p;
    return (y < 0.f) ? -p : p;
}

// extract channel C of 4 consecutive NHWC pixels held in 3 float4s (wave-uniform c)
__device__ __forceinline__ float4 extract_c(float4 f0, float4 f1, float4 f2, int c) {
    if (c == 0) return make_float4(f0.x, f0.w, f1.z, f2.y);
    if (c == 1) return make_float4(f0.y, f1.x, f1.w, f2.z);
    return make_float4(f0.z, f1.y, f2.x, f2.w);
}

__global__ __launch_bounds__(THREADS) void work_kernel(const float* __restrict__ xin,
                                                       const float* __restrict__ xout,
                                                       const float* __restrict__ mean,
                                                       const float* __restrict__ logvar,
                                                       float* __restrict__ out) {
    __shared__ __align__(16) float SMEM[SMEM_FLOATS];
    __shared__ float sm8[8];
    const int tid = threadIdx.x;
    const int gid = blockIdx.x;
    float acc = 0.f;

    if (gid == 3648) {
        // ---- KLD block ----
        float a = 0.f;
        for (int i = tid; i < BATCH * LDIM; i += THREADS) {
            float m = mean[i], lv = logvar[i];
            a += -0.5f * (1.f + lv - expf(lv) - m * m) * (1.f / 32.f);
        }
        #pragma unroll
        for (int o = 32; o > 0; o >>= 1) a += __shfl_down(a, o, 64);
        if ((tid & 63) == 0) sm8[tid >> 6] = a;
        __syncthreads();
        if (tid == 0) {
            float s = sm8[0];
            #pragma unroll
            for (int i = 1; i < 8; ++i) s += sm8[i];
            atomicAdd(out, s);
        }
        return;
    }

    const int grp = gid / 114, k = gid % 114;

    if (k < 57) {
        // ---- STFT role: (b, c, prg); rows 8*prg..+15 ----
        int idx = grp * 57 + k;
        int b   = idx / 57;
        int rem = idx % 57;
        int c   = rem / 19;
        int prg = rem % 19;
        int row0 = prg * 8;
        __half2* HXY = (__half2*)SMEM;                 // [r 0..15][col] = (x, y)
        __half2* RD  = (__half2*)(SMEM + STFT_RD_OFF); // [r][vv][img][pc]

        // stage: 640 tasks (r, colq); read NHWC both imgs, extract c, pack half2
        for (int t = tid; t < 640; t += THREADS) {
            int rr = t / 40;
            int cq = t % 40;
            size_t off = ((size_t)(b * 160 + row0 + rr) * 160 + cq * 4) * 3;
            const float4* qa = (const float4*)(xin + off);
            const float4* qb = (const float4*)(xout + off);
            float4 a0 = qa[0], a1 = qa[1], a2 = qa[2];
            float4 b0 = qb[0], b1 = qb[1], b2 = qb[2];
            float4 xa = extract_c(a0, a1, a2, c);
            float4 xb = extract_c(b0, b1, b2, c);
            __half2 h[4] __attribute__((aligned(16)));
            h[0] = __floats2half2_rn(xa.x, xb.x);
            h[1] = __floats2half2_rn(xa.y, xb.y);
            h[2] = __floats2half2_rn(xa.z, xb.z);
            h[3] = __floats2half2_rn(xa.w, xb.w);
            *(float4*)&HXY[rr * 160 + cq * 4] = *(float4*)h;
        }
        __syncthreads();

        // phase A: 608 tasks (r, pc); both images per task; real-input symmetry
        for (int t = tid; t < 608; t += THREADS) {
            int pc = t % 38;
            int r  = t / 38;
            float4 raw[3];
            raw[0] = *(const float4*)&HXY[r * 160 + pc * 4];
            raw[1] = *(const float4*)&HXY[r * 160 + pc * 4 + 4];
            raw[2] = *(const float4*)&HXY[r * 160 + pc * 4 + 8];
            const __half2* hp = (const __half2*)raw;
            float xa[12], xb[12];
            #pragma unroll
            for (int j = 0; j < 12; ++j) {
                float2 xy = __half22float2(hp[j]);
                xa[j] = xy.x; xb[j] = xy.y;
            }
            #pragma unroll
            for (int img = 0; img < 2; ++img) {
                const float* x = img ? xb : xa;
                float ev[5] = {x[1]+x[11], x[2]+x[10], x[3]+x[9], x[4]+x[8], x[5]+x[7]};
                float ov[5] = {x[1]-x[11], x[2]-x[10], x[3]-x[9], x[4]-x[8], x[5]-x[7]};
                #pragma unroll
                for (int vv = 0; vv < 5; ++vv) {
                    int v = vv + 1;
                    float re = x[0] + ((v & 1) ? -x[6] : x[6]);
                    float im = 0.f;
                    #pragma unroll
                    for (int j = 1; j <= 5; ++j) {
                        int kk = (v * j) % 12;           // compile-time
                        re = fmaf(ev[j-1], TWC[kk], re);
                        im = fmaf(ov[j-1], TWS[kk], im);
                    }
                    RD[((r * 5 + vv) * 2 + img) * 38 + pc] = __floats2half2_rn(re, im);
                }
            }
        }
        __syncthreads();

        // phase B: 380 tasks (g, vv, pc); half-period fold, all 5 u per task
        if (tid < 380) {
            int pc = tid % 38;
            int vv = (tid / 38) % 5;
            int g  = tid / 190;
            float FR0[5] = {0,0,0,0,0}, FI0[5] = {0,0,0,0,0};
            float FR1[5] = {0,0,0,0,0}, FI1[5] = {0,0,0,0,0};
            #pragma unroll
            for (int i = 0; i < 6; ++i) {
                int rlo = 4 * g + i, rhi = rlo + 6;
                float2 a0 = __half22float2(RD[((rlo * 5 + vv) * 2 + 0) * 38 + pc]);
                float2 a6 = __half22float2(RD[((rhi * 5 + vv) * 2 + 0) * 38 + pc]);
                float2 b0 = __half22float2(RD[((rlo * 5 + vv) * 2 + 1) * 38 + pc]);
                float2 b6 = __half22float2(RD[((rhi * 5 + vv) * 2 + 1) * 38 + pc]);
                float spR0 = a0.x + a6.x, spI0 = a0.y + a6.y;
                float smR0 = a0.x - a6.x, smI0 = a0.y - a6.y;
                float spR1 = b0.x + b6.x, spI1 = b0.y + b6.y;
                float smR1 = b0.x - b6.x, smI1 = b0.y - b6.y;
                #pragma unroll
                for (int uu = 0; uu < 5; ++uu) {
                    int u = uu + 1;
                    int kk = (u * i) % 12;               // compile-time twiddle
                    float cu = TWC[kk], su = TWS[kk];
                    float sR0 = (u & 1) ? smR0 : spR0, sI0 = (u & 1) ? smI0 : spI0;
                    float sR1 = (u & 1) ? smR1 : spR1, sI1 = (u & 1) ? smI1 : spI1;
                    FR0[uu] = fmaf(cu, sR0, fmaf(-su, sI0, FR0[uu]));
                    FI0[uu] = fmaf(cu, sI0, fmaf( su, sR0, FI0[uu]));
                    FR1[uu] = fmaf(cu, sR1, fmaf(-su, sI1, FR1[uu]));
                    FI1[uu] = fmaf(cu, sI1, fmaf( su, sR1, FI1[uu]));
                }
            }
            #pragma unroll
            for (int uu = 0; uu < 5; ++uu) {
                float aI = fast_atan2f(FI0[uu], FR0[uu] + 1e-8f);
                float aO = fast_atan2f(FI1[uu], FR1[uu] + 1e-8f);
                float mI = sqrtf(FR0[uu] * FR0[uu] + FI0[uu] * FI0[uu]);
                float mO = sqrtf(FR1[uu] * FR1[uu] + FI1[uu] * FI1[uu]);
                float ff = (float)((uu + 1) * (vv + 1)) * 0.04f;
                acc += ff * (fabsf(aO - aI) + fabsf(mO - mI));
            }
        }
        acc *= 1e-4f / 32.f;
    } else {
        // ---- SSIM role: (b, c, 8-row tile) ----
        int idx = grp * 57 + (k - 57);
        int b    = idx / 57;
        int rem  = idx % 57;
        int c    = rem / 19;
        int tile = rem % 19;
        int r0 = tile * 8;
        __half2* HXY = (__half2*)SMEM;                 // [rr 0..17][col] = (x, y)

        // stage: 720 tasks (rr, colq); NHWC both imgs, extract c, pack half2
        for (int t = tid; t < 720; t += THREADS) {
            int rr = t / 40;
            int cq = t % 40;
            int row = r0 + rr;
            float4 xa = make_float4(0.f, 0.f, 0.f, 0.f);
            float4 xb = make_float4(0.f, 0.f, 0.f, 0.f);
            if (row < NPIX) {
                size_t off = ((size_t)(b * 160 + row) * 160 + cq * 4) * 3;
                const float4* qa = (const float4*)(xin + off);
                const float4* qb = (const float4*)(xout + off);
                float4 a0 = qa[0], a1 = qa[1], a2 = qa[2];
                float4 b0 = qb[0], b1 = qb[1], b2 = qb[2];
                xa = extract_c(a0, a1, a2, c);
                xb = extract_c(b0, b1, b2, c);
            }
            __half2 h[4] __attribute__((aligned(16)));
            h[0] = __floats2half2_rn(xa.x, xb.x);
            h[1] = __floats2half2_rn(xa.y, xb.y);
            h[2] = __floats2half2_rn(xa.z, xb.z);
            h[3] = __floats2half2_rn(xa.w, xb.w);
            *(float4*)&HXY[rr * 160 + cq * 4] = *(float4*)h;
        }
        __syncthreads();

        // phase V: vertical 11-tap, 320 tasks; 11 b128 reads/task (4 cols, both imgs)
        for (int t = tid; t < 320; t += THREADS) {
            int orow = t / 40;
            int cbase = (t % 40) * 4;
            float ax[4] = {0,0,0,0}, ay[4] = {0,0,0,0};
            float axx[4] = {0,0,0,0}, ayy[4] = {0,0,0,0}, axy[4] = {0,0,0,0};
            #pragma unroll
            for (int kk = 0; kk < 11; ++kk) {
                float4 raw = *(const float4*)&HXY[(orow + kk) * 160 + cbase];
                const __half2* hp = (const __half2*)&raw;
                float wg = GW[kk];
                #pragma unroll
                for (int o = 0; o < 4; ++o) {
                    float2 xy = __half22float2(hp[o]);
                    ax[o]  += wg * xy.x;          ay[o]  += wg * xy.y;
                    axx[o] += wg * (xy.x * xy.x); ayy[o] += wg * (xy.y * xy.y);
                    axy[o] += wg * (xy.x * xy.y);
                }
            }
            int base = SSIM_V_OFF + orow * 160 + cbase;
            *(float4*)&SMEM[base + 0 * VSTRIDE] = make_float4(ax[0],  ax[1],  ax[2],  ax[3]);
            *(float4*)&SMEM[base + 1 * VSTRIDE] = make_float4(ay[0],  ay[1],  ay[2],  ay[3]);
            *(float4*)&SMEM[base + 2 * VSTRIDE] = make_float4(axx[0], axx[1], axx[2], axx[3]);
            *(float4*)&SMEM[base + 3 * VSTRIDE] = make_float4(ayy[0], ayy[1], ayy[2], ayy[3]);
            *(float4*)&SMEM[base + 4 * VSTRIDE] = make_float4(axy[0], axy[1], axy[2], axy[3]);
        }
        __syncthreads();

        // phase H: 600 tasks (8 orows x 75 col-pairs), stride-2 windows (2-way, free)
        for (int t = tid; t < 600; t += THREADS) {
            int orow = t / 75;
            int oc = (t % 75) * 2;
            float st[5][2];
            #pragma unroll
            for (int p = 0; p < 5; ++p) {
                float vals[12];
                #pragma unroll
                for (int kk = 0; kk < 12; ++kk)
                    vals[kk] = SMEM[SSIM_V_OFF + p * VSTRIDE + orow * 160 + oc + kk];
                float s0 = 0.f, s1 = 0.f;
                #pragma unroll
                for (int kk = 0; kk < 11; ++kk) {
                    s0 += GW[kk] * vals[kk];
                    s1 += GW[kk] * vals[kk + 1];
                }
                st[p][0] = s0; st[p][1] = s1;
            }
            const float c1 = 1e-4f, c2 = 9e-4f;
            if (r0 + orow < OUT_SZ) {
                #pragma unroll
                for (int o = 0; o < 2; ++o) {
                    float mx = st[0][o], my = st[1][o];
                    float vx = st[2][o] - mx * mx;
                    float vy = st[3][o] - my * my;
                    float cv = st[4][o] - mx * my;
                    float lum = (2.f * mx * my + c1) / (mx * mx + my * my + c1);
                    float cs  = (2.f * cv + c2) / (vx + vy + c2);
                    acc += lum * cs;
                }
            }
        }
        acc *= 1.f / (32.f * 150.f * 150.f * 3.f);
    }

    // block reduce (8 waves) -> one device-scope atomic per block
    #pragma unroll
    for (int o = 32; o > 0; o >>= 1) acc += __shfl_down(acc, o, 64);
    if ((tid & 63) == 0) sm8[tid >> 6] = acc;
    __syncthreads();
    if (tid == 0) {
        float s = sm8[0];
        #pragma unroll
        for (int i = 1; i < 8; ++i) s += sm8[i];
        atomicAdd(out, s);
    }
}

extern "C" void kernel_launch(void* const* d_in, const int* in_sizes, int n_in,
                              void* d_out, int out_size, void* d_ws, size_t ws_size,
                              hipStream_t stream) {
    const float* mean   = (const float*)d_in[0];
    const float* logvar = (const float*)d_in[1];
    const float* xin    = (const float*)d_in[2];
    const float* xout   = (const float*)d_in[3];
    float* out = (float*)d_out;

    hipMemsetAsync(out, 0, sizeof(float), stream);   // graph-capturable memset node
    work_kernel<<<N_BLOCKS, THREADS, 0, stream>>>(xin, xout, mean, logvar, out);
}

// Round 15
// 123.797 us; speedup vs baseline: 1.2734x; 1.0377x over previous
//
#include <hip/hip_runtime.h>
#include <hip/hip_fp16.h>
#include <math.h>

#define BATCH 32
#define NPIX 160
#define LDIM 128
#define OUT_SZ 150        // 160 - 11 + 1

#define THREADS 512
// one fused block per (b, c, tile): 32*3*19 = 1824 work blocks + 1 KLD block
#define N_BLOCKS 1825
// LDS carve (float units):
//   HXY stage: 18*160 half2 = 2880 fl-equiv (11.5 KB)
//   scratch region at 2880: stft RD (6080 half2 = 3040 fl) OR ssim V planes (5*1296 fl)
#define SCRATCH_OFF 2880
#define VSTRIDE 1296
#define SMEM_FLOATS 9360   // 37.4 KB -> 4 blocks/CU

// e^{-i*2pi*k/12}; entries 0 / ±0.5 / ±0.866 / ±1 -> FMAs fold at compile time
__device__ constexpr float TWC[12] = { 1.f, 0.86602540f, 0.5f, 0.f, -0.5f, -0.86602540f,
                                      -1.f,-0.86602540f,-0.5f, 0.f,  0.5f,  0.86602540f};
__device__ constexpr float TWS[12] = { 0.f,-0.5f,-0.86602540f,-1.f,-0.86602540f,-0.5f,
                                       0.f, 0.5f, 0.86602540f, 1.f, 0.86602540f, 0.5f};

__device__ constexpr float GW[11] = {0.00102838f, 0.00759876f, 0.03600076f, 0.10936070f,
                                     0.21300554f, 0.26601172f, 0.21300554f, 0.10936070f,
                                     0.03600076f, 0.00759876f, 0.00102838f};

// minimax atan poly, max err ~1e-6 rad (validated R7/R9-R14, absmax 0.0)
__device__ __forceinline__ float fast_atan2f(float y, float x) {
    float ax = fabsf(x), ay = fabsf(y);
    float mx = fmaxf(ax, ay), mn = fminf(ax, ay);
    float z = mn / mx;
    float z2 = z * z;
    float p = fmaf(z2, -0.01172120f, 0.05265332f);
    p = fmaf(z2, p, -0.11643287f);
    p = fmaf(z2, p, 0.19354346f);
    p = fmaf(z2, p, -0.33262347f);
    p = fmaf(z2, p, 0.99997726f);
    p = p * z;
    if (ay > ax) p = 1.57079632679489662f - p;
    if (x < 0.f) p = 3.14159265358979323f - p;
    return (y < 0.f) ? -p : p;
}

// extract channel C of 4 consecutive NHWC pixels held in 3 float4s (wave-uniform c)
__device__ __forceinline__ float4 extract_c(float4 f0, float4 f1, float4 f2, int c) {
    if (c == 0) return make_float4(f0.x, f0.w, f1.z, f2.y);
    if (c == 1) return make_float4(f0.y, f1.x, f1.w, f2.z);
    return make_float4(f0.z, f1.y, f2.x, f2.w);
}

__global__ __launch_bounds__(THREADS) void work_kernel(const float* __restrict__ xin,
                                                       const float* __restrict__ xout,
                                                       const float* __restrict__ mean,
                                                       const float* __restrict__ logvar,
                                                       float* __restrict__ out) {
    __shared__ __align__(16) float SMEM[SMEM_FLOATS];
    __shared__ float sm8[8];
    const int tid = threadIdx.x;
    const int gid = blockIdx.x;
    float acc = 0.f;

    if (gid == 1824) {
        // ---- KLD block ----
        float a = 0.f;
        for (int i = tid; i < BATCH * LDIM; i += THREADS) {
            float m = mean[i], lv = logvar[i];
            a += -0.5f * (1.f + lv - expf(lv) - m * m) * (1.f / 32.f);
        }
        #pragma unroll
        for (int o = 32; o > 0; o >>= 1) a += __shfl_down(a, o, 64);
        if ((tid & 63) == 0) sm8[tid >> 6] = a;
        __syncthreads();
        if (tid == 0) {
            float s = sm8[0];
            #pragma unroll
            for (int i = 1; i < 8; ++i) s += sm8[i];
            atomicAdd(out, s);
        }
        return;
    }

    // fused work block: (b, c, tile); tile covers ssim rows 8t..8t+17, stft rows 8t..8t+15
    int b    = gid / 57;
    int rem  = gid % 57;
    int c    = rem / 19;
    int tile = rem % 19;
    int r0 = tile * 8;
    __half2* HXY = (__half2*)SMEM;                   // [rr 0..17][col] = (x, y)
    __half2* RD  = (__half2*)(SMEM + SCRATCH_OFF);   // stft scratch [r][vv][img][pc]

    // ---- stage: 720 tasks (rr, colq); NHWC both imgs, extract c, pack half2 ----
    for (int t = tid; t < 720; t += THREADS) {
        int rr = t / 40;
        int cq = t % 40;
        int row = r0 + rr;
        float4 xa = make_float4(0.f, 0.f, 0.f, 0.f);
        float4 xb = make_float4(0.f, 0.f, 0.f, 0.f);
        if (row < NPIX) {
            size_t off = ((size_t)(b * 160 + row) * 160 + cq * 4) * 3;
            const float4* qa = (const float4*)(xin + off);
            const float4* qb = (const float4*)(xout + off);
            float4 a0 = qa[0], a1 = qa[1], a2 = qa[2];
            float4 b0 = qb[0], b1 = qb[1], b2 = qb[2];
            xa = extract_c(a0, a1, a2, c);
            xb = extract_c(b0, b1, b2, c);
        }
        __half2 h[4] __attribute__((aligned(16)));
        h[0] = __floats2half2_rn(xa.x, xb.x);
        h[1] = __floats2half2_rn(xa.y, xb.y);
        h[2] = __floats2half2_rn(xa.z, xb.z);
        h[3] = __floats2half2_rn(xa.w, xb.w);
        *(float4*)&HXY[rr * 160 + cq * 4] = *(float4*)h;
    }
    __syncthreads();

    // ---- stft phase A: 608 tasks (r 0..15, pc); both images; real-input symmetry ----
    for (int t = tid; t < 608; t += THREADS) {
        int pc = t % 38;
        int r  = t / 38;
        float4 raw[3];
        raw[0] = *(const float4*)&HXY[r * 160 + pc * 4];
        raw[1] = *(const float4*)&HXY[r * 160 + pc * 4 + 4];
        raw[2] = *(const float4*)&HXY[r * 160 + pc * 4 + 8];
        const __half2* hp = (const __half2*)raw;
        float xa[12], xb[12];
        #pragma unroll
        for (int j = 0; j < 12; ++j) {
            float2 xy = __half22float2(hp[j]);
            xa[j] = xy.x; xb[j] = xy.y;
        }
        #pragma unroll
        for (int img = 0; img < 2; ++img) {
            const float* x = img ? xb : xa;
            float ev[5] = {x[1]+x[11], x[2]+x[10], x[3]+x[9], x[4]+x[8], x[5]+x[7]};
            float ov[5] = {x[1]-x[11], x[2]-x[10], x[3]-x[9], x[4]-x[8], x[5]-x[7]};
            #pragma unroll
            for (int vv = 0; vv < 5; ++vv) {
                int v = vv + 1;
                float re = x[0] + ((v & 1) ? -x[6] : x[6]);
                float im = 0.f;
                #pragma unroll
                for (int j = 1; j <= 5; ++j) {
                    int kk = (v * j) % 12;           // compile-time
                    re = fmaf(ev[j-1], TWC[kk], re);
                    im = fmaf(ov[j-1], TWS[kk], im);
                }
                RD[((r * 5 + vv) * 2 + img) * 38 + pc] = __floats2half2_rn(re, im);
            }
        }
    }
    __syncthreads();

    // ---- stft phase B: 380 tasks (g, vv, pc); half-period fold, all 5 u per task ----
    if (tid < 380) {
        int pc = tid % 38;
        int vv = (tid / 38) % 5;
        int g  = tid / 190;
        float FR0[5] = {0,0,0,0,0}, FI0[5] = {0,0,0,0,0};
        float FR1[5] = {0,0,0,0,0}, FI1[5] = {0,0,0,0,0};
        #pragma unroll
        for (int i = 0; i < 6; ++i) {
            int rlo = 4 * g + i, rhi = rlo + 6;
            float2 a0 = __half22float2(RD[((rlo * 5 + vv) * 2 + 0) * 38 + pc]);
            float2 a6 = __half22float2(RD[((rhi * 5 + vv) * 2 + 0) * 38 + pc]);
            float2 b0 = __half22float2(RD[((rlo * 5 + vv) * 2 + 1) * 38 + pc]);
            float2 b6 = __half22float2(RD[((rhi * 5 + vv) * 2 + 1) * 38 + pc]);
            float spR0 = a0.x + a6.x, spI0 = a0.y + a6.y;
            float smR0 = a0.x - a6.x, smI0 = a0.y - a6.y;
            float spR1 = b0.x + b6.x, spI1 = b0.y + b6.y;
            float smR1 = b0.x - b6.x, smI1 = b0.y - b6.y;
            #pragma unroll
            for (int uu = 0; uu < 5; ++uu) {
                int u = uu + 1;
                int kk = (u * i) % 12;               // compile-time twiddle
                float cu = TWC[kk], su = TWS[kk];
                float sR0 = (u & 1) ? smR0 : spR0, sI0 = (u & 1) ? smI0 : spI0;
                float sR1 = (u & 1) ? smR1 : spR1, sI1 = (u & 1) ? smI1 : spI1;
                FR0[uu] = fmaf(cu, sR0, fmaf(-su, sI0, FR0[uu]));
                FI0[uu] = fmaf(cu, sI0, fmaf( su, sR0, FI0[uu]));
                FR1[uu] = fmaf(cu, sR1, fmaf(-su, sI1, FR1[uu]));
                FI1[uu] = fmaf(cu, sI1, fmaf( su, sR1, FI1[uu]));
            }
        }
        float sacc = 0.f;
        #pragma unroll
        for (int uu = 0; uu < 5; ++uu) {
            float aI = fast_atan2f(FI0[uu], FR0[uu] + 1e-8f);
            float aO = fast_atan2f(FI1[uu], FR1[uu] + 1e-8f);
            float mI = sqrtf(FR0[uu] * FR0[uu] + FI0[uu] * FI0[uu]);
            float mO = sqrtf(FR1[uu] * FR1[uu] + FI1[uu] * FI1[uu]);
            float ff = (float)((uu + 1) * (vv + 1)) * 0.04f;
            sacc += ff * (fabsf(aO - aI) + fabsf(mO - mI));
        }
        acc += sacc * (1e-4f / 32.f);
    }
    __syncthreads();   // RD dead; V planes reuse the scratch region

    // ---- ssim phase V: vertical 11-tap, 320 tasks; writes V planes over scratch ----
    for (int t = tid; t < 320; t += THREADS) {
        int orow = t / 40;
        int cbase = (t % 40) * 4;
        float ax[4] = {0,0,0,0}, ay[4] = {0,0,0,0};
        float axx[4] = {0,0,0,0}, ayy[4] = {0,0,0,0}, axy[4] = {0,0,0,0};
        #pragma unroll
        for (int kk = 0; kk < 11; ++kk) {
            float4 raw = *(const float4*)&HXY[(orow + kk) * 160 + cbase];
            const __half2* hp = (const __half2*)&raw;
            float wg = GW[kk];
            #pragma unroll
            for (int o = 0; o < 4; ++o) {
                float2 xy = __half22float2(hp[o]);
                ax[o]  += wg * xy.x;          ay[o]  += wg * xy.y;
                axx[o] += wg * (xy.x * xy.x); ayy[o] += wg * (xy.y * xy.y);
                axy[o] += wg * (xy.x * xy.y);
            }
        }
        int base = SCRATCH_OFF + orow * 160 + cbase;
        *(float4*)&SMEM[base + 0 * VSTRIDE] = make_float4(ax[0],  ax[1],  ax[2],  ax[3]);
        *(float4*)&SMEM[base + 1 * VSTRIDE] = make_float4(ay[0],  ay[1],  ay[2],  ay[3]);
        *(float4*)&SMEM[base + 2 * VSTRIDE] = make_float4(axx[0], axx[1], axx[2], axx[3]);
        *(float4*)&SMEM[base + 3 * VSTRIDE] = make_float4(ayy[0], ayy[1], ayy[2], ayy[3]);
        *(float4*)&SMEM[base + 4 * VSTRIDE] = make_float4(axy[0], axy[1], axy[2], axy[3]);
    }
    __syncthreads();

    // ---- ssim phase H: 600 tasks (8 orows x 75 col-pairs), stride-2 windows ----
    {
        float hacc = 0.f;
        for (int t = tid; t < 600; t += THREADS) {
            int orow = t / 75;
            int oc = (t % 75) * 2;
            float st[5][2];
            #pragma unroll
            for (int p = 0; p < 5; ++p) {
                float vals[12];
                #pragma unroll
                for (int kk = 0; kk < 12; ++kk)
                    vals[kk] = SMEM[SCRATCH_OFF + p * VSTRIDE + orow * 160 + oc + kk];
                float s0 = 0.f, s1 = 0.f;
                #pragma unroll
                for (int kk = 0; kk < 11; ++kk) {
                    s0 += GW[kk] * vals[kk];
                    s1 += GW[kk] * vals[kk + 1];
                }
                st[p][0] = s0; st[p][1] = s1;
            }
            const float c1 = 1e-4f, c2 = 9e-4f;
            if (r0 + orow < OUT_SZ) {
                #pragma unroll
                for (int o = 0; o < 2; ++o) {
                    float mx = st[0][o], my = st[1][o];
                    float vx = st[2][o] - mx * mx;
                    float vy = st[3][o] - my * my;
                    float cv = st[4][o] - mx * my;
                    float lum = (2.f * mx * my + c1) / (mx * mx + my * my + c1);
                    float cs  = (2.f * cv + c2) / (vx + vy + c2);
                    hacc += lum * cs;
                }
            }
        }
        acc += hacc * (1.f / (32.f * 150.f * 150.f * 3.f));
    }

    // ---- block reduce (8 waves) -> one device-scope atomic per block ----
    #pragma unroll
    for (int o = 32; o > 0; o >>= 1) acc += __shfl_down(acc, o, 64);
    if ((tid & 63) == 0) sm8[tid >> 6] = acc;
    __syncthreads();
    if (tid == 0) {
        float s = sm8[0];
        #pragma unroll
        for (int i = 1; i < 8; ++i) s += sm8[i];
        atomicAdd(out, s);
    }
}

extern "C" void kernel_launch(void* const* d_in, const int* in_sizes, int n_in,
                              void* d_out, int out_size, void* d_ws, size_t ws_size,
                              hipStream_t stream) {
    const float* mean   = (const float*)d_in[0];
    const float* logvar = (const float*)d_in[1];
    const float* xin    = (const float*)d_in[2];
    const float* xout   = (const float*)d_in[3];
    float* out = (float*)d_out;

    hipMemsetAsync(out, 0, sizeof(float), stream);   // graph-capturable memset node
    work_kernel<<<N_BLOCKS, THREADS, 0, stream>>>(xin, xout, mean, logvar, out);
}